// Round 6
// baseline (252.090 us; speedup 1.0000x reference)
//
#include <hip/hip_runtime.h>

typedef unsigned int uint;
typedef unsigned short ushort;
typedef __attribute__((ext_vector_type(2))) _Float16 h2;   // packed half2
typedef __attribute__((ext_vector_type(8))) _Float16 h8;   // MFMA A/B frag (4 VGPRs)
typedef __attribute__((ext_vector_type(4))) float f32x4;   // MFMA C/D frag

#define CAP   64     // bucket capacity per node
#define NPB   96     // nodes per bin (6 GEMM tiles)
#define NBIN  521    // ceil(50000/96)
#define NTILE 6      // NPB/16
#define STR   68     // LDS A row stride in dwords
#define CAPB  2048   // edge capacity per bin (mean 1536, +13 sigma)
#define EPB   4096   // edges per partition block (1024 thr x 4)
#define NBLK_PART 196

__device__ __forceinline__ uint pack_h2(float a, float b) {
  h2 v = {(_Float16)a, (_Float16)b};
  return __builtin_bit_cast(uint, v);
}
__device__ __forceinline__ float h_lo(uint u) {
  return (float)__builtin_bit_cast(_Float16, (ushort)(u & 0xffffu));
}
__device__ __forceinline__ float h_hi(uint u) {
  return (float)__builtin_bit_cast(_Float16, (ushort)(u >> 16));
}

// ---- partition edges into dst-bins + GLOBAL deg histogram + fp16 xr + W1 pack ----
__global__ __launch_bounds__(1024) void k_part(
    const int* __restrict__ src, const int* __restrict__ dst,
    int* __restrict__ binCnt, int* __restrict__ deg, uint* __restrict__ binData,
    const float2* __restrict__ x2, uint* __restrict__ xr,
    const float* __restrict__ W1, uint* __restrict__ wpack, int N, int E) {
  __shared__ int hist[NBIN];
  __shared__ int base[NBIN];
  int t = threadIdx.x;
  int gid = blockIdx.x * 1024 + t;

  // W1 fp16 B-frag pack (blocks 0..3)
  if (gid < 4096) {
    int kk = gid >> 10, rem = gid & 1023, ntile = rem >> 6, ln = rem & 63;
    int quad = ln >> 4, nn = ntile * 16 + (ln & 15);
    uint w[4];
#pragma unroll
    for (int jp = 0; jp < 4; ++jp) {
      int k = kk * 32 + quad * 8 + 2 * jp;
      w[jp] = pack_h2(W1[k * 256 + nn], W1[(k + 1) * 256 + nn]);
    }
    *(uint4*)&wpack[gid * 4] = make_uint4(w[0], w[1], w[2], w[3]);
  }

  for (int i = t; i < NBIN; i += 1024) hist[i] = 0;
  __syncthreads();
  int s4[4], d4[4], bb[4], r4[4];
  bool v4[4];
#pragma unroll
  for (int j = 0; j < 4; ++j) {
    int e = blockIdx.x * EPB + j * 1024 + t;   // coalesced
    v4[j] = e < E;
    if (v4[j]) {
      s4[j] = src[e];
      d4[j] = dst[e];
      bb[j] = d4[j] / NPB;
      r4[j] = atomicAdd(&hist[bb[j]], 1);      // count AND rank in one pass
      atomicAdd(&deg[d4[j]], 1);               // global in-degree (exact)
    }
  }
  __syncthreads();
  for (int i = t; i < NBIN; i += 1024) {
    int h = hist[i];
    base[i] = h ? atomicAdd(&binCnt[i], h) : 0;
  }
  __syncthreads();
#pragma unroll
  for (int j = 0; j < 4; ++j) {
    if (v4[j]) {
      int idx = base[bb[j]] + r4[j];
      if (idx < CAPB)
        binData[bb[j] * CAPB + idx] = (uint)s4[j] | ((uint)d4[j] << 16);
    }
  }
  // fp16 convert of x (UNSCALED — no deg dependency): 3.2M uints streamed
  int tot = N * 64;
  for (int i = gid; i < tot; i += NBLK_PART * 1024) {
    float2 f = x2[i];
    xr[i] = pack_h2(f.x, f.y);
  }
}

// ---- FUSED: bucket build (iv packed in entry) -> gather (fp32 acc) -> MFMA -> cz ----
// 512 thr = 8 waves = 2 groups x 4; launch_bounds(512,4): 2 blocks/CU, VGPR cap 128.
__global__ __launch_bounds__(512, 4) void k_agg1(
    const uint* __restrict__ binData, const int* __restrict__ binCnt,
    const int* __restrict__ deg, const uint* __restrict__ xr,
    uint* __restrict__ colg, const uint* __restrict__ wpack,
    const float* __restrict__ b1, const float* __restrict__ W2,
    float* __restrict__ cz, int N) {
  __shared__ uint col_l[NPB * CAP];    // 24576 B, entry = (u16 src | fp16 inv_s)
  __shared__ int cnt_l[NPB];
  __shared__ uint As[2 * 16 * STR];    // 8704 B
  __shared__ float red[2 * 64];
  int b = blockIdx.x, t = threadIdx.x;
  int lo = b * NPB;
  int nh = min(NPB, N - lo);

  for (int i = t; i < NPB; i += 512) cnt_l[i] = 0;
  for (int i = t; i < NPB * CAP; i += 512) col_l[i] = 0;  // pad -> iv=0 (inert)
  __syncthreads();
  int m = min(binCnt[b], CAPB);
  const uint* bd = &binData[(size_t)b * CAPB];
  for (int e = t; e < m; e += 512) {
    uint pr = bd[e];
    int sv = pr & 0xffffu;
    int dl = (int)(pr >> 16) - lo;     // in [0, NPB)
    int p = atomicAdd(&cnt_l[dl], 1);
    if (p < CAP) {
      float ivf = rsqrtf((float)(deg[sv] + 1));   // deg complete (kernel boundary)
      ushort hb = __builtin_bit_cast(ushort, (_Float16)ivf);
      col_l[dl * CAP + p] = (uint)sv | ((uint)hb << 16);
    }
  }
  __syncthreads();
  // col writeout for layer-2 kernel
  if (nh > 0) {
    uint* cg = colg + (size_t)lo * CAP;
    int nu = nh * CAP;
    for (int i = t; i < nu; i += 512) cg[i] = col_l[i];
  }

  int wave = t >> 6, lane = t & 63;
  int wg = wave & 3, g = wave >> 2;
  int quad = lane >> 4, mrow = lane & 15;
  for (int tt = 0; tt < 3; ++tt) {
    int T = tt * 2 + g;                // group 0: tiles 0,2,4; group 1: 1,3,5
    int m0 = T * 16;
    int e4[4], ce4[4];
    float2 ac[4];
    float ivd[4];
#pragma unroll
    for (int r = 0; r < 4; ++r) {
      int nl = m0 + wg * 4 + r;
      if (nl < nh) {
        int c = cnt_l[nl];
        e4[r] = min(c, CAP);
        ce4[r] = (int)col_l[nl * CAP + lane];
        ivd[r] = rsqrtf((float)(c + 1));
        uint u = xr[(size_t)(lo + nl) * 64 + lane];   // self loop (unscaled)
        ac[r] = make_float2(ivd[r] * h_lo(u), ivd[r] * h_hi(u));
      } else {
        e4[r] = 0; ce4[r] = 0; ivd[r] = 0.f;
        ac[r] = make_float2(0.f, 0.f);
      }
    }
    int emax = max(max(e4[0], e4[1]), max(e4[2], e4[3]));
    for (int p = 0; p < emax; p += 8) {
      uint pr8[4][8];                  // wave-uniform (SGPR-resident)
      uint pv[4][8];
      // issue phase: up to 32 loads in flight across the 4 nodes
#pragma unroll
      for (int r = 0; r < 4; ++r) {
        if (p < e4[r]) {               // wave-uniform branch
#pragma unroll
          for (int j = 0; j < 8; ++j) {
            uint pr = (uint)__builtin_amdgcn_readlane(ce4[r], p + j);
            pr8[r][j] = pr;
            pv[r][j] = xr[(size_t)(pr & 0xffffu) * 64 + lane];
          }
        }
      }
      // accumulate phase: fp32 fma with per-edge fp16 inv_s (from entry hi bits)
#pragma unroll
      for (int r = 0; r < 4; ++r) {
        if (p < e4[r]) {
          int lim = e4[r] - p;
#pragma unroll
          for (int j = 0; j < 8; ++j) {
            float ivf = (j < lim) ? h_hi(pr8[r][j]) : 0.f;
            uint u = pv[r][j];
            ac[r].x = fmaf(ivf, h_lo(u), ac[r].x);
            ac[r].y = fmaf(ivf, h_hi(u), ac[r].y);
          }
        }
      }
    }
#pragma unroll
    for (int r = 0; r < 4; ++r) {
      As[(g * 16 + wg * 4 + r) * STR + lane] =
          pack_h2(ivd[r] * ac[r].x, ivd[r] * ac[r].y);
    }
    __syncthreads();
    f32x4 acc[4];
#pragma unroll
    for (int nt = 0; nt < 4; ++nt) acc[nt] = (f32x4){0.f, 0.f, 0.f, 0.f};
#pragma unroll
    for (int kk = 0; kk < 4; ++kk) {
      h8 af = *(const h8*)&As[(g * 16 + mrow) * STR + kk * 16 + quad * 4];
#pragma unroll
      for (int nt = 0; nt < 4; ++nt) {
        int ntile = wg * 4 + nt;
        h8 bf = *(const h8*)&wpack[((kk * 16 + ntile) * 64 + lane) * 4];
        acc[nt] = __builtin_amdgcn_mfma_f32_16x16x32_f16(af, bf, acc[nt], 0, 0, 0);
      }
    }
    float partial[4] = {0.f, 0.f, 0.f, 0.f};
#pragma unroll
    for (int nt = 0; nt < 4; ++nt) {
      int c = (wg * 4 + nt) * 16 + mrow;
      float b1c = b1[c], w2c = W2[c];
#pragma unroll
      for (int r = 0; r < 4; ++r) {
        float h = fmaxf(acc[nt][r] + b1c, 0.f);
        partial[r] = fmaf(h, w2c, partial[r]);
      }
    }
#pragma unroll
    for (int r = 0; r < 4; ++r) {
      float p = partial[r];
      p += __shfl_xor(p, 1); p += __shfl_xor(p, 2);
      p += __shfl_xor(p, 4); p += __shfl_xor(p, 8);
      if (mrow == 0) red[g * 64 + wg * 16 + quad * 4 + r] = p;
    }
    __syncthreads();
    if (wg == 0 && lane < 16) {
      int nl = m0 + lane;
      if (nl < nh) {
        float s = red[g * 64 + lane] + red[g * 64 + 16 + lane] +
                  red[g * 64 + 32 + lane] + red[g * 64 + 48 + lane];
        cz[lo + nl] = rsqrtf((float)(cnt_l[nl] + 1)) * s;
      }
    }
    // next iter's As/red writes are fenced by its own first __syncthreads
  }
}

// ---- layer-2 aggregation: 4 lanes per node over packed u32 buckets ----
__global__ void k_agg2(const uint* __restrict__ colg, const int* __restrict__ deg,
                       const float* __restrict__ cz, const float* __restrict__ b2,
                       float* __restrict__ out, int N) {
  int gdx = blockIdx.x * blockDim.x + threadIdx.x;
  int node = gdx >> 2, q = gdx & 3;
  if (node >= N) return;
  int c = deg[node];
  int e = min(c, CAP);
  float acc = (q == 0) ? cz[node] : 0.f;
  const uint* cp = &colg[(size_t)node * CAP];
#pragma unroll 4
  for (int p = q; p < e; p += 4) acc += cz[cp[p] & 0xffffu];
  acc += __shfl_xor(acc, 1);
  acc += __shfl_xor(acc, 2);
  if (q == 0) out[node] = rsqrtf((float)(c + 1)) * acc + b2[0];
}

extern "C" void kernel_launch(void* const* d_in, const int* in_sizes, int n_in,
                              void* d_out, int out_size, void* d_ws, size_t ws_size,
                              hipStream_t stream) {
  const float2* x2 = (const float2*)d_in[0];
  const int*    ei = (const int*)d_in[1];
  const float*  W1 = (const float*)d_in[2];
  const float*  b1 = (const float*)d_in[3];
  const float*  W2 = (const float*)d_in[4];
  const float*  b2 = (const float*)d_in[5];
  int N = in_sizes[0] / 128;
  int E = in_sizes[1] / 2;
  const int* src = ei;
  const int* dst = ei + E;
  float* out = (float*)d_out;

  char* w = (char*)d_ws;
  size_t o = 0;
  auto carve = [&](size_t bytes) { char* p = w + o; o += (bytes + 255) & ~(size_t)255; return p; };
  int*  binCnt  = (int*)  carve((size_t)NBIN * 4);            // adjacent to deg:
  int*  deg     = (int*)  carve((size_t)N * 4);               // one memset covers both
  uint* binData = (uint*) carve((size_t)NBIN * CAPB * 4);     // 4.3 MB
  uint* colg    = (uint*) carve((size_t)N * CAP * 4);         // 12.8 MB (packed s|iv)
  uint* xr      = (uint*) carve((size_t)N * 64 * 4);          // 12.8 MB fp16 x
  uint* wpack   = (uint*) carve(16384 * 4);
  float* cz     = (float*)carve((size_t)N * 4);

  // zero binCnt (padded to 2304) + deg in ONE memset (contiguous carves)
  hipMemsetAsync(binCnt, 0, 2304 + (size_t)N * 4, stream);

  int nblk_p = (E + EPB - 1) / EPB;                           // 196
  k_part<<<nblk_p, 1024, 0, stream>>>(src, dst, binCnt, deg, binData,
                                      x2, xr, W1, wpack, N, E);

  k_agg1<<<NBIN, 512, 0, stream>>>(binData, binCnt, deg, xr, colg, wpack,
                                   b1, W2, cz, N);

  long long tot2 = (long long)N * 4;
  k_agg2<<<(int)((tot2 + 255) / 256), 256, 0, stream>>>(colg, deg, cz, b2, out, N);
}

// Round 7
// 173.650 us; speedup vs baseline: 1.4517x; 1.4517x over previous
//
#include <hip/hip_runtime.h>

typedef unsigned int uint;
typedef unsigned short ushort;
typedef __attribute__((ext_vector_type(2))) _Float16 h2;   // packed half2 (v_pk_*_f16)
typedef __attribute__((ext_vector_type(8))) _Float16 h8;   // MFMA A/B frag (4 VGPRs)
typedef __attribute__((ext_vector_type(4))) float f32x4;   // MFMA C/D frag

#define CAP   64    // bucket capacity per node (deg~Poisson(16), P(>64) ~ 1e-26)
#define BM16  16    // rows per GEMM tile
#define STR   68    // LDS A row stride in dwords
#define EPB   4096  // edges per partition block (1024 thr x 4)
#define NBLK_PART 196

__device__ __forceinline__ uint pack_h2(float a, float b) {
  h2 v = {(_Float16)a, (_Float16)b};
  return __builtin_bit_cast(uint, v);
}

// ---- DIRECT scatter partition: one global atomic + one 2B store per edge ----
// (round-6 lesson: 800k scattered global atomics are cheap; the binData/bucketize
//  two-level pipeline they replaced cost a full kernel + 6.4MB round-trip)
// fused: W1 fp16 B-frag pack (blocks 0..3) | fp16 convert of x (unscaled)
__global__ __launch_bounds__(1024) void k_part(
    const int* __restrict__ src, const int* __restrict__ dst,
    int* __restrict__ cnt, ushort* __restrict__ col,
    const float2* __restrict__ x2, uint* __restrict__ xr,
    const float* __restrict__ W1, uint* __restrict__ wpack, int N, int E) {
  int t = threadIdx.x;
  int gid = blockIdx.x * 1024 + t;

  // W1 fp16 B-frag pack (blocks 0..3)
  // wpack[(kk*16+ntile)*64+ln]: B[k=kk*32+quad*8+j][n=ntile*16+(ln&15)], j=0..7
  if (gid < 4096) {
    int kk = gid >> 10, rem = gid & 1023, ntile = rem >> 6, ln = rem & 63;
    int quad = ln >> 4, nn = ntile * 16 + (ln & 15);
    uint w[4];
#pragma unroll
    for (int jp = 0; jp < 4; ++jp) {
      int k = kk * 32 + quad * 8 + 2 * jp;
      w[jp] = pack_h2(W1[k * 256 + nn], W1[(k + 1) * 256 + nn]);
    }
    *(uint4*)&wpack[gid * 4] = make_uint4(w[0], w[1], w[2], w[3]);
  }

  // edge scatter: cnt[d] ends as exact in-degree; slot order nondeterministic
  // (set is deterministic; fp16/fp32 reorder noise ~1e-6 << tolerance)
#pragma unroll
  for (int j = 0; j < 4; ++j) {
    int e = blockIdx.x * EPB + j * 1024 + t;   // coalesced read
    if (e < E) {
      int s = src[e], d = dst[e];
      int p = atomicAdd(&cnt[d], 1);           // device-scope, random addr
      if (p < CAP) col[(size_t)d * CAP + p] = (ushort)s;
    }
  }

  // fp16 convert of x (UNSCALED — no cnt dependency): 3.2M uints streamed
  int tot = N * 64;
  for (int i = gid; i < tot; i += NBLK_PART * 1024) {
    float2 f = x2[i];
    xr[i] = pack_h2(f.x, f.y);
  }
}

// ---- FUSED: interleaved 4-node gather with per-edge fp16 scale -> MFMA -> cz ----
// per-lane iv_s prefetch: cnt is 200KB (L2-resident) so the 64 scattered 4B loads
// per row are cheap; inner loop = readlane(s) + readlane(iv) + load + v_pk_fma.
__global__ __launch_bounds__(256, 4) void k_agg_gemm(
    const uint* __restrict__ xr, const ushort* __restrict__ col,
    const int* __restrict__ cnt, const uint* __restrict__ wpack,
    const float* __restrict__ b1, const float* __restrict__ W2,
    float* __restrict__ cz, int N) {
  __shared__ uint As[BM16 * STR];
  __shared__ float red[64];
  int t = threadIdx.x, wave = t >> 6, lane = t & 63;
  int m0 = blockIdx.x * BM16;

  int e4[4], ce4[4];
  uint ivu4[4];                        // fp16 iv_src duplicated in both halves
  h2 ac[4];
  float invd[4];
#pragma unroll
  for (int r = 0; r < 4; ++r) {
    int node = m0 + wave * 4 + r;
    if (node < N) {
      int c = cnt[node];
      e4[r] = min(c, CAP);
      invd[r] = rsqrtf((float)(c + 1));
      int ce = (int)col[(size_t)node * CAP + lane];   // coalesced 128 B row
      ce4[r] = ce;
      // lane-masked: dead slots get iv=0 so readlane(iv) is 0 for tail edges
      float ivs = (lane < e4[r]) ? rsqrtf((float)(cnt[ce] + 1)) : 0.f;
      ushort hb = __builtin_bit_cast(ushort, (_Float16)ivs);
      ivu4[r] = (uint)hb | ((uint)hb << 16);
      uint u = xr[(size_t)node * 64 + lane];          // self loop (unscaled)
      _Float16 ivh = (_Float16)invd[r];
      ac[r] = __builtin_bit_cast(h2, u) * (h2){ivh, ivh};
    } else {
      e4[r] = 0; ce4[r] = 0; ivu4[r] = 0; invd[r] = 0.f;
      ac[r] = (h2){(_Float16)0.f, (_Float16)0.f};
    }
  }
  int emax = max(max(e4[0], e4[1]), max(e4[2], e4[3]));
  for (int p = 0; p < emax; p += 8) {
    uint pv[4][8];
    // issue phase: up to 32 loads in flight across the 4 nodes
#pragma unroll
    for (int r = 0; r < 4; ++r) {
      if (p < e4[r]) {                 // wave-uniform branch
#pragma unroll
        for (int j = 0; j < 8; ++j) {
          int s = __builtin_amdgcn_readlane(ce4[r], p + j);
          pv[r][j] = xr[(size_t)s * 64 + lane];
        }
      }
    }
    // accumulate phase: one v_pk_fma_f16 per edge (iv broadcast via readlane)
#pragma unroll
    for (int r = 0; r < 4; ++r) {
      if (p < e4[r]) {
        int lim = e4[r] - p;
#pragma unroll
        for (int j = 0; j < 8; ++j) {
          uint ivp = (uint)__builtin_amdgcn_readlane((int)ivu4[r], p + j);
          uint u = (j < lim) ? pv[r][j] : 0u;   // mask garbage (could be NaN bits)
          ac[r] += __builtin_bit_cast(h2, u) * __builtin_bit_cast(h2, ivp);
        }
      }
    }
  }
#pragma unroll
  for (int r = 0; r < 4; ++r) {
    float ax = invd[r] * (float)ac[r].x;
    float ay = invd[r] * (float)ac[r].y;
    As[(wave * 4 + r) * STR + lane] = pack_h2(ax, ay);
  }
  __syncthreads();

  int quad = lane >> 4, mrow = lane & 15;
  f32x4 acc[4];
#pragma unroll
  for (int nt = 0; nt < 4; ++nt) acc[nt] = (f32x4){0.f, 0.f, 0.f, 0.f};
#pragma unroll
  for (int kk = 0; kk < 4; ++kk) {
    h8 af = *(const h8*)&As[mrow * STR + kk * 16 + quad * 4];
#pragma unroll
    for (int nt = 0; nt < 4; ++nt) {
      int ntile = wave * 4 + nt;
      h8 bf = *(const h8*)&wpack[((kk * 16 + ntile) * 64 + lane) * 4];
      acc[nt] = __builtin_amdgcn_mfma_f32_16x16x32_f16(af, bf, acc[nt], 0, 0, 0);
    }
  }

  float partial[4] = {0.f, 0.f, 0.f, 0.f};
#pragma unroll
  for (int nt = 0; nt < 4; ++nt) {
    int c = (wave * 4 + nt) * 16 + mrow;
    float b1c = b1[c], w2c = W2[c];
#pragma unroll
    for (int r = 0; r < 4; ++r) {
      float h = fmaxf(acc[nt][r] + b1c, 0.f);
      partial[r] = fmaf(h, w2c, partial[r]);
    }
  }
#pragma unroll
  for (int r = 0; r < 4; ++r) {
    float p = partial[r];
    p += __shfl_xor(p, 1); p += __shfl_xor(p, 2);
    p += __shfl_xor(p, 4); p += __shfl_xor(p, 8);
    if (mrow == 0) red[wave * 16 + quad * 4 + r] = p;
  }
  __syncthreads();
  if (t < 16) {
    int node = m0 + t;
    if (node < N) {
      float s = red[t] + red[16 + t] + red[32 + t] + red[48 + t];
      cz[node] = rsqrtf((float)(cnt[node] + 1)) * s;  // layer-2 prescale
    }
  }
}

// ---- layer-2 aggregation: 4 lanes per node over u16 buckets ----
__global__ void k_agg2(const ushort* __restrict__ col, const int* __restrict__ cnt,
                       const float* __restrict__ cz, const float* __restrict__ b2,
                       float* __restrict__ out, int N) {
  int g = blockIdx.x * blockDim.x + threadIdx.x;
  int node = g >> 2, q = g & 3;
  if (node >= N) return;
  int e = min(cnt[node], CAP);
  float acc = (q == 0) ? cz[node] : 0.f;
  const ushort* cp = &col[(size_t)node * CAP];
#pragma unroll 4
  for (int p = q; p < e; p += 4) acc += cz[cp[p]];   // cz = 200KB, L2-hot
  acc += __shfl_xor(acc, 1);
  acc += __shfl_xor(acc, 2);
  if (q == 0) out[node] = rsqrtf((float)(cnt[node] + 1)) * acc + b2[0];
}

extern "C" void kernel_launch(void* const* d_in, const int* in_sizes, int n_in,
                              void* d_out, int out_size, void* d_ws, size_t ws_size,
                              hipStream_t stream) {
  const float2* x2 = (const float2*)d_in[0];
  const int*    ei = (const int*)d_in[1];
  const float*  W1 = (const float*)d_in[2];
  const float*  b1 = (const float*)d_in[3];
  const float*  W2 = (const float*)d_in[4];
  const float*  b2 = (const float*)d_in[5];
  int N = in_sizes[0] / 128;
  int E = in_sizes[1] / 2;
  const int* src = ei;
  const int* dst = ei + E;
  float* out = (float*)d_out;

  char* w = (char*)d_ws;
  size_t o = 0;
  auto carve = [&](size_t bytes) { char* p = w + o; o += (bytes + 255) & ~(size_t)255; return p; };
  // order matters for garbage-read safety: unfilled col slots hold arbitrary u16
  // (<=65535); gather may speculatively read cnt[s] (<=262KB -> lands in col) and
  // xr[s*64+..] (<=16.8MB from xr base -> lands in pad). Values are discarded.
  int*    cnt   = (int*)   carve((size_t)N * 4);          // 200 KB
  ushort* col   = (ushort*)carve((size_t)N * CAP * 2);    // 6.4 MB
  uint*   xr    = (uint*)  carve((size_t)N * 64 * 4);     // 12.8 MB fp16 x
  char*   pad   =          carve((size_t)4352 * 1024);    // 4.25 MB safety pad
  uint*   wpack = (uint*)  carve(16384 * 4);
  float*  cz    = (float*) carve((size_t)N * 4);
  (void)pad;

  hipMemsetAsync(cnt, 0, (size_t)N * sizeof(int), stream);

  int nblk_p = (E + EPB - 1) / EPB;                       // 196
  k_part<<<nblk_p, 1024, 0, stream>>>(src, dst, cnt, col, x2, xr, W1, wpack, N, E);

  k_agg_gemm<<<(N + BM16 - 1) / BM16, 256, 0, stream>>>(
      xr, col, cnt, wpack, b1, W2, cz, N);

  long long tot2 = (long long)N * 4;
  k_agg2<<<(int)((tot2 + 255) / 256), 256, 0, stream>>>(col, cnt, cz, b2, out, N);
}